// Round 4
// baseline (73.446 us; speedup 1.0000x reference)
//
#include <hip/hip_runtime.h>

typedef float v2f __attribute__((ext_vector_type(2)));

namespace {
constexpr int B   = 8;
constexpr int TQ  = 256;
constexpr int TK  = 256;
constexpr int DQK = 512;
constexpr int DV  = 512;
constexpr int H   = 256;
constexpr int QB  = 4;           // q rows per score/pv block
constexpr int NH  = 2;           // h splits in score kernel
constexpr int HS  = H / NH;      // 128
constexpr float C2LOG2E = 2.8853900817779268f; // 2*log2(e)
constexpr float LOG2E   = 1.4426950408889634f;
} // namespace

// Fused projections (pk_fma accumulate):
//  z==0: qpc[b*TQ+q][h]            = (queries @ Wq)[row][h] * 2log2e
//  z==1: kpc4[b][h/4][k][h&3]      = (keys    @ Wk)[row][h] * 2log2e
__global__ __launch_bounds__(256)
void proj_kernel(const float* __restrict__ Q, const float* __restrict__ Kin,
                 const float* __restrict__ Wq, const float* __restrict__ Wk,
                 float* __restrict__ qpc, float* __restrict__ kpc4)
{
    constexpr int BM = 64, BN = 32, BK = 16;
    __shared__ float As[BK][BM];   // A tile stored transposed
    __shared__ float Bs[BK][BN];

    const bool kside = (blockIdx.z == 1);
    const float* A = kside ? Kin : Q;
    const float* W = kside ? Wk  : Wq;
    const int m0 = blockIdx.x * BM;
    const int n0 = blockIdx.y * BN;
    const int tid = threadIdx.x;
    const int tx = tid & 15;        // n dir (16 threads * 2 cols)
    const int ty = tid >> 4;        // m dir (16 threads * 4 rows)
    const int ar = tid >> 2, ac4 = (tid & 3) * 4;
    const int br = tid >> 4, bc2 = (tid & 15) * 2;

    v2f acc2[4] = {};
    for (int k0 = 0; k0 < DQK; k0 += BK) {
        float4 av = *(const float4*)(A + (m0 + ar) * DQK + k0 + ac4);
        float2 bv = *(const float2*)(W + (k0 + br) * H + n0 + bc2);
        __syncthreads();  // protect previous iteration's LDS reads
        As[ac4 + 0][ar] = av.x;
        As[ac4 + 1][ar] = av.y;
        As[ac4 + 2][ar] = av.z;
        As[ac4 + 3][ar] = av.w;
        *(float2*)&Bs[br][bc2] = bv;
        __syncthreads();
        #pragma unroll
        for (int kk = 0; kk < BK; ++kk) {
            float4 a = *(const float4*)&As[kk][ty * 4];
            v2f b2 = *(const v2f*)&Bs[kk][tx * 2];
            v2f ax = {a.x, a.x}, ay = {a.y, a.y}, az = {a.z, a.z}, aw = {a.w, a.w};
            acc2[0] = __builtin_elementwise_fma(ax, b2, acc2[0]);
            acc2[1] = __builtin_elementwise_fma(ay, b2, acc2[1]);
            acc2[2] = __builtin_elementwise_fma(az, b2, acc2[2]);
            acc2[3] = __builtin_elementwise_fma(aw, b2, acc2[3]);
        }
    }

    if (!kside) {
        #pragma unroll
        for (int i = 0; i < 4; ++i) {
            v2f v = acc2[i] * C2LOG2E;
            *(v2f*)(qpc + (m0 + ty * 4 + i) * H + n0 + tx * 2) = v;
        }
    } else {
        const int h = n0 + tx * 2;   // even
        #pragma unroll
        for (int i = 0; i < 4; ++i) {
            const int row = m0 + ty * 4 + i;   // = b*256 + k
            const int bb = row >> 8, kk = row & 255;
            v2f v = acc2[i] * C2LOG2E;
            *(v2f*)(kpc4 + ((bb * (H / 4) + (h >> 2)) * TK + kk) * 4 + (h & 3)) = v;
        }
    }
}

// Scores (partial over an h-half). Block = (b, qgroup of 4, hh). Thread = k.
// partial[blk][q][k] = sum_{h in half} wv[h] * rcp(exp2(qpc+kpc) + 1)
__global__ __launch_bounds__(256)
void score_kernel(const float* __restrict__ qpc, const float* __restrict__ kpc4,
                  const float* __restrict__ wv, float* __restrict__ partial)
{
    __shared__ float qlds[QB][HS];   // 2 KB
    __shared__ float wlds[HS];       // 0.5 KB

    const int blk = blockIdx.x;          // (b*64+qg)*NH + hh
    const int hh  = blk & (NH - 1);
    const int bqg = blk / NH;            // b*64 + qg
    const int b   = bqg >> 6, qg = bqg & 63;
    const int tid = threadIdx.x;         // k
    const int h0  = hh * HS;

    for (int i = tid; i < QB * HS; i += 256)
        qlds[i >> 7][i & 127] = qpc[(b * TQ + qg * QB + (i >> 7)) * H + h0 + (i & 127)];
    if (tid < HS) wlds[tid] = wv[h0 + tid];
    __syncthreads();

    const float4* kc = (const float4*)kpc4 + (b * (H / 4) + h0 / 4) * TK + tid;
    float acc[QB] = {};
    #pragma unroll 4
    for (int h4 = 0; h4 < HS / 4; ++h4) {
        float4 kv = kc[h4 * TK];
        float4 w4 = *(const float4*)&wlds[h4 * 4];
        #pragma unroll
        for (int q = 0; q < QB; ++q) {
            float4 q4 = *(const float4*)&qlds[q][h4 * 4];
            acc[q] = fmaf(w4.x, __builtin_amdgcn_rcpf(__builtin_amdgcn_exp2f(q4.x + kv.x) + 1.0f), acc[q]);
            acc[q] = fmaf(w4.y, __builtin_amdgcn_rcpf(__builtin_amdgcn_exp2f(q4.y + kv.y) + 1.0f), acc[q]);
            acc[q] = fmaf(w4.z, __builtin_amdgcn_rcpf(__builtin_amdgcn_exp2f(q4.z + kv.z) + 1.0f), acc[q]);
            acc[q] = fmaf(w4.w, __builtin_amdgcn_rcpf(__builtin_amdgcn_exp2f(q4.w + kv.w) + 1.0f), acc[q]);
        }
    }

    float* pp = partial + blk * (QB * TK);
    #pragma unroll
    for (int q = 0; q < QB; ++q) pp[q * TK + tid] = acc[q];
}

// Combine + softmax + PV. Block = (b, qgroup of 4, vh). 256 threads.
// Thread = (kq = tid>>6 k-quarter, lane*4 = float4 col chunk in the DV-half).
__global__ __launch_bounds__(256)
void pv_kernel(const float* __restrict__ partial, const float* __restrict__ values,
               float* __restrict__ out)
{
    __shared__ float elds[QB][TK];          // 4 KB
    __shared__ float rowsum[QB];
    __shared__ float accbuf[4][QB][64][4];  // 16 KB

    const int blk = blockIdx.x;     // (b*64+qg)*2 + vh
    const int vh  = blk & 1;
    const int bqg = blk >> 1;
    const int b   = bqg >> 6, qg = bqg & 63;
    const int tid = threadIdx.x;

    const float* p0 = partial + bqg * NH * (QB * TK);
    for (int i = tid; i < QB * TK; i += 256) {
        float s = p0[i] + p0[QB * TK + i];       // NH == 2
        elds[i >> 8][i & 255] = -2.0f * s;
    }
    __syncthreads();

    // softmax: wave q handles row q
    {
        const int q = tid >> 6, lane = tid & 63;
        float4 v = *(const float4*)&elds[q][lane * 4];
        float m = fmaxf(fmaxf(v.x, v.y), fmaxf(v.z, v.w));
        #pragma unroll
        for (int off = 1; off < 64; off <<= 1)
            m = fmaxf(m, __shfl_xor(m, off));
        float e0 = __builtin_amdgcn_exp2f((v.x - m) * LOG2E);
        float e1 = __builtin_amdgcn_exp2f((v.y - m) * LOG2E);
        float e2 = __builtin_amdgcn_exp2f((v.z - m) * LOG2E);
        float e3 = __builtin_amdgcn_exp2f((v.w - m) * LOG2E);
        float s = (e0 + e1) + (e2 + e3);
        #pragma unroll
        for (int off = 1; off < 64; off <<= 1)
            s += __shfl_xor(s, off);
        __syncthreads();   // everyone done reading elds logits
        *(float4*)&elds[q][lane * 4] = make_float4(e0, e1, e2, e3);
        if (lane == 0) rowsum[q] = s;
    }
    __syncthreads();

    // PV over this block's DV-half, k split across 4 wave-groups
    const int kq = tid >> 6, lane = tid & 63;
    const float* vb = values + (b * TK + kq * 64) * DV + vh * 256 + lane * 4;
    v2f o[QB][2] = {};
    for (int kk0 = 0; kk0 < 64; kk0 += 4) {
        float4 v0 = *(const float4*)(vb + (kk0 + 0) * DV);
        float4 v1 = *(const float4*)(vb + (kk0 + 1) * DV);
        float4 v2 = *(const float4*)(vb + (kk0 + 2) * DV);
        float4 v3 = *(const float4*)(vb + (kk0 + 3) * DV);
        #pragma unroll
        for (int q = 0; q < QB; ++q) {
            float4 p = *(const float4*)&elds[q][kq * 64 + kk0];
            v2f p0v = {p.x, p.x}, p1v = {p.y, p.y}, p2v = {p.z, p.z}, p3v = {p.w, p.w};
            v2f v0lo = {v0.x, v0.y}, v0hi = {v0.z, v0.w};
            v2f v1lo = {v1.x, v1.y}, v1hi = {v1.z, v1.w};
            v2f v2lo = {v2.x, v2.y}, v2hi = {v2.z, v2.w};
            v2f v3lo = {v3.x, v3.y}, v3hi = {v3.z, v3.w};
            o[q][0] = __builtin_elementwise_fma(p0v, v0lo, o[q][0]);
            o[q][1] = __builtin_elementwise_fma(p0v, v0hi, o[q][1]);
            o[q][0] = __builtin_elementwise_fma(p1v, v1lo, o[q][0]);
            o[q][1] = __builtin_elementwise_fma(p1v, v1hi, o[q][1]);
            o[q][0] = __builtin_elementwise_fma(p2v, v2lo, o[q][0]);
            o[q][1] = __builtin_elementwise_fma(p2v, v2hi, o[q][1]);
            o[q][0] = __builtin_elementwise_fma(p3v, v3lo, o[q][0]);
            o[q][1] = __builtin_elementwise_fma(p3v, v3hi, o[q][1]);
        }
    }
    #pragma unroll
    for (int q = 0; q < QB; ++q) {
        *(v2f*)&accbuf[kq][q][lane][0] = o[q][0];
        *(v2f*)&accbuf[kq][q][lane][2] = o[q][1];
    }
    __syncthreads();

    // reduce k-quarters: thread = (q = tid>>6, c4 = tid&63)
    {
        const int q = tid >> 6, c4 = tid & 63;
        float4 s0 = *(const float4*)&accbuf[0][q][c4][0];
        float4 s1 = *(const float4*)&accbuf[1][q][c4][0];
        float4 s2 = *(const float4*)&accbuf[2][q][c4][0];
        float4 s3 = *(const float4*)&accbuf[3][q][c4][0];
        float inv = __builtin_amdgcn_rcpf(rowsum[q]);
        float4 r;
        r.x = (s0.x + s1.x + s2.x + s3.x) * inv;
        r.y = (s0.y + s1.y + s2.y + s3.y) * inv;
        r.z = (s0.z + s1.z + s2.z + s3.z) * inv;
        r.w = (s0.w + s1.w + s2.w + s3.w) * inv;
        *(float4*)(out + (b * TQ + qg * QB + q) * DV + vh * 256 + c4 * 4) = r;
    }
}

extern "C" void kernel_launch(void* const* d_in, const int* in_sizes, int n_in,
                              void* d_out, int out_size, void* d_ws, size_t ws_size,
                              hipStream_t stream)
{
    const float* queries = (const float*)d_in[0];
    const float* keys    = (const float*)d_in[1];
    const float* values  = (const float*)d_in[2];
    const float* Wq      = (const float*)d_in[3];
    const float* Wk      = (const float*)d_in[4];
    const float* wv      = (const float*)d_in[5];
    float* out     = (float*)d_out;
    float* qpc     = (float*)d_ws;                    // (B*TQ, H)        2 MB
    float* kpc4    = qpc + B * TQ * H;                // (B, H/4, TK, 4)  2 MB
    float* partial = kpc4 + B * H * TK;               // (B*64*NH, 4, TK) 4 MB

    dim3 gproj(B * TQ / 64, H / 32, 2);
    proj_kernel<<<gproj, 256, 0, stream>>>(queries, keys, Wq, Wk, qpc, kpc4);
    score_kernel<<<B * (TQ / QB) * NH, 256, 0, stream>>>(qpc, kpc4, wv, partial);
    pv_kernel<<<B * (TQ / QB) * 2, 256, 0, stream>>>(partial, values, out);
}

// Round 5
// 73.333 us; speedup vs baseline: 1.0015x; 1.0015x over previous
//
#include <hip/hip_runtime.h>

typedef float v2f __attribute__((ext_vector_type(2)));

namespace {
constexpr int B   = 8;
constexpr int TQ  = 256;
constexpr int TK  = 256;
constexpr int DQK = 512;
constexpr int DV  = 512;
constexpr int H   = 256;
constexpr int QB  = 4;           // q rows per score/pv block
constexpr int NH  = 2;           // h splits in score kernel
constexpr int HS  = H / NH;      // 128
constexpr float C2LOG2E = 2.8853900817779268f; // 2*log2(e)
constexpr float LOG2E   = 1.4426950408889634f;
} // namespace

// Fused projections, 4x4 register tile + global->reg prefetch:
//  z==0: qpc[b*TQ+q][h]       = (queries @ Wq)[row][h] * 2log2e
//  z==1: kpc4[b][h/4][k][h&3] = (keys    @ Wk)[row][h] * 2log2e
__global__ __launch_bounds__(256)
void proj_kernel(const float* __restrict__ Q, const float* __restrict__ Kin,
                 const float* __restrict__ Wq, const float* __restrict__ Wk,
                 float* __restrict__ qpc, float* __restrict__ kpc4)
{
    constexpr int BM = 64, BN = 64, BK = 16;
    __shared__ float As[BK][BM];   // A tile stored transposed (k-major)
    __shared__ float Bs[BK][BN];

    const bool kside = (blockIdx.z == 1);
    const float* A = kside ? Kin : Q;
    const float* W = kside ? Wk  : Wq;
    const int m0 = blockIdx.x * BM;
    const int n0 = blockIdx.y * BN;
    const int tid = threadIdx.x;
    const int tx = tid & 15;        // col group (4 cols)
    const int ty = tid >> 4;        // row group (4 rows)
    const int ar = tid >> 2, ac4 = (tid & 3) * 4;   // A load: row ar, k ac4..+3
    const int br = tid >> 4, bc4 = (tid & 15) * 4;  // B load: k br, col bc4..+3

    // prefetch first tiles into registers
    float4 av = *(const float4*)(A + (m0 + ar) * DQK + ac4);
    float4 bv = *(const float4*)(W + br * H + n0 + bc4);

    v2f acc[4][2] = {};
    for (int k0 = 0; k0 < DQK; k0 += BK) {
        __syncthreads();   // previous iteration's LDS reads complete
        As[ac4 + 0][ar] = av.x;
        As[ac4 + 1][ar] = av.y;
        As[ac4 + 2][ar] = av.z;
        As[ac4 + 3][ar] = av.w;
        *(float4*)&Bs[br][bc4] = bv;
        __syncthreads();
        if (k0 + BK < DQK) {   // prefetch next tiles (hidden under fma chain)
            av = *(const float4*)(A + (m0 + ar) * DQK + k0 + BK + ac4);
            bv = *(const float4*)(W + (k0 + BK + br) * H + n0 + bc4);
        }
        #pragma unroll
        for (int kk = 0; kk < BK; ++kk) {
            float4 a4 = *(const float4*)&As[kk][ty * 4];
            float4 b4 = *(const float4*)&Bs[kk][tx * 4];
            v2f blo = {b4.x, b4.y}, bhi = {b4.z, b4.w};
            v2f ax = {a4.x, a4.x}, ay = {a4.y, a4.y};
            v2f az = {a4.z, a4.z}, aw = {a4.w, a4.w};
            acc[0][0] = __builtin_elementwise_fma(ax, blo, acc[0][0]);
            acc[0][1] = __builtin_elementwise_fma(ax, bhi, acc[0][1]);
            acc[1][0] = __builtin_elementwise_fma(ay, blo, acc[1][0]);
            acc[1][1] = __builtin_elementwise_fma(ay, bhi, acc[1][1]);
            acc[2][0] = __builtin_elementwise_fma(az, blo, acc[2][0]);
            acc[2][1] = __builtin_elementwise_fma(az, bhi, acc[2][1]);
            acc[3][0] = __builtin_elementwise_fma(aw, blo, acc[3][0]);
            acc[3][1] = __builtin_elementwise_fma(aw, bhi, acc[3][1]);
        }
    }

    if (!kside) {
        #pragma unroll
        for (int i = 0; i < 4; ++i) {
            float4 r;
            r.x = acc[i][0].x * C2LOG2E;
            r.y = acc[i][0].y * C2LOG2E;
            r.z = acc[i][1].x * C2LOG2E;
            r.w = acc[i][1].y * C2LOG2E;
            *(float4*)(qpc + (m0 + ty * 4 + i) * H + n0 + tx * 4) = r;
        }
    } else {
        const int h = n0 + tx * 4;     // multiple of 4
        #pragma unroll
        for (int i = 0; i < 4; ++i) {
            const int row = m0 + ty * 4 + i;   // = b*256 + k
            const int bb = row >> 8, kk = row & 255;
            float4 r;
            r.x = acc[i][0].x * C2LOG2E;
            r.y = acc[i][0].y * C2LOG2E;
            r.z = acc[i][1].x * C2LOG2E;
            r.w = acc[i][1].y * C2LOG2E;
            *(float4*)(kpc4 + ((bb * (H / 4) + (h >> 2)) * TK + kk) * 4) = r;
        }
    }
}

// Scores (partial over an h-half). Block = (b, qgroup of 4, hh). Thread = k.
// partial[blk][q][k] = sum_{h in half} wv[h] * rcp(exp2(qpc+kpc) + 1)
__global__ __launch_bounds__(256)
void score_kernel(const float* __restrict__ qpc, const float* __restrict__ kpc4,
                  const float* __restrict__ wv, float* __restrict__ partial)
{
    __shared__ float qlds[QB][HS];   // 2 KB
    __shared__ float wlds[HS];       // 0.5 KB

    const int blk = blockIdx.x;          // (b*64+qg)*NH + hh
    const int hh  = blk & (NH - 1);
    const int bqg = blk / NH;            // b*64 + qg
    const int b   = bqg >> 6, qg = bqg & 63;
    const int tid = threadIdx.x;         // k
    const int h0  = hh * HS;

    for (int i = tid; i < QB * HS; i += 256)
        qlds[i >> 7][i & 127] = qpc[(b * TQ + qg * QB + (i >> 7)) * H + h0 + (i & 127)];
    if (tid < HS) wlds[tid] = wv[h0 + tid];
    __syncthreads();

    const float4* kc = (const float4*)kpc4 + (b * (H / 4) + h0 / 4) * TK + tid;
    float acc[QB] = {};
    #pragma unroll 4
    for (int h4 = 0; h4 < HS / 4; ++h4) {
        float4 kv = kc[h4 * TK];
        float4 w4 = *(const float4*)&wlds[h4 * 4];
        #pragma unroll
        for (int q = 0; q < QB; ++q) {
            float4 q4 = *(const float4*)&qlds[q][h4 * 4];
            acc[q] = fmaf(w4.x, __builtin_amdgcn_rcpf(__builtin_amdgcn_exp2f(q4.x + kv.x) + 1.0f), acc[q]);
            acc[q] = fmaf(w4.y, __builtin_amdgcn_rcpf(__builtin_amdgcn_exp2f(q4.y + kv.y) + 1.0f), acc[q]);
            acc[q] = fmaf(w4.z, __builtin_amdgcn_rcpf(__builtin_amdgcn_exp2f(q4.z + kv.z) + 1.0f), acc[q]);
            acc[q] = fmaf(w4.w, __builtin_amdgcn_rcpf(__builtin_amdgcn_exp2f(q4.w + kv.w) + 1.0f), acc[q]);
        }
    }

    float* pp = partial + blk * (QB * TK);
    #pragma unroll
    for (int q = 0; q < QB; ++q) pp[q * TK + tid] = acc[q];
}

// Combine + softmax + PV. Block = (b, qgroup of 4, vh). 256 threads.
__global__ __launch_bounds__(256)
void pv_kernel(const float* __restrict__ partial, const float* __restrict__ values,
               float* __restrict__ out)
{
    __shared__ float elds[QB][TK];          // 4 KB
    __shared__ float rowsum[QB];
    __shared__ float accbuf[4][QB][64][4];  // 16 KB

    const int blk = blockIdx.x;     // (b*64+qg)*2 + vh
    const int vh  = blk & 1;
    const int bqg = blk >> 1;
    const int b   = bqg >> 6, qg = bqg & 63;
    const int tid = threadIdx.x;

    const float* p0 = partial + bqg * NH * (QB * TK);
    for (int i = tid; i < QB * TK; i += 256) {
        float s = p0[i] + p0[QB * TK + i];       // NH == 2
        elds[i >> 8][i & 255] = -2.0f * s;
    }
    __syncthreads();

    // softmax: wave q handles row q
    {
        const int q = tid >> 6, lane = tid & 63;
        float4 v = *(const float4*)&elds[q][lane * 4];
        float m = fmaxf(fmaxf(v.x, v.y), fmaxf(v.z, v.w));
        #pragma unroll
        for (int off = 1; off < 64; off <<= 1)
            m = fmaxf(m, __shfl_xor(m, off));
        float e0 = __builtin_amdgcn_exp2f((v.x - m) * LOG2E);
        float e1 = __builtin_amdgcn_exp2f((v.y - m) * LOG2E);
        float e2 = __builtin_amdgcn_exp2f((v.z - m) * LOG2E);
        float e3 = __builtin_amdgcn_exp2f((v.w - m) * LOG2E);
        float s = (e0 + e1) + (e2 + e3);
        #pragma unroll
        for (int off = 1; off < 64; off <<= 1)
            s += __shfl_xor(s, off);
        __syncthreads();   // everyone done reading elds logits
        *(float4*)&elds[q][lane * 4] = make_float4(e0, e1, e2, e3);
        if (lane == 0) rowsum[q] = s;
    }
    __syncthreads();

    // PV over this block's DV-half, k split across 4 wave-groups
    const int kq = tid >> 6, lane = tid & 63;
    const float* vb = values + (b * TK + kq * 64) * DV + vh * 256 + lane * 4;
    v2f o[QB][2] = {};
    for (int kk0 = 0; kk0 < 64; kk0 += 4) {
        float4 v0 = *(const float4*)(vb + (kk0 + 0) * DV);
        float4 v1 = *(const float4*)(vb + (kk0 + 1) * DV);
        float4 v2 = *(const float4*)(vb + (kk0 + 2) * DV);
        float4 v3 = *(const float4*)(vb + (kk0 + 3) * DV);
        #pragma unroll
        for (int q = 0; q < QB; ++q) {
            float4 p = *(const float4*)&elds[q][kq * 64 + kk0];
            v2f p0v = {p.x, p.x}, p1v = {p.y, p.y}, p2v = {p.z, p.z}, p3v = {p.w, p.w};
            v2f v0lo = {v0.x, v0.y}, v0hi = {v0.z, v0.w};
            v2f v1lo = {v1.x, v1.y}, v1hi = {v1.z, v1.w};
            v2f v2lo = {v2.x, v2.y}, v2hi = {v2.z, v2.w};
            v2f v3lo = {v3.x, v3.y}, v3hi = {v3.z, v3.w};
            o[q][0] = __builtin_elementwise_fma(p0v, v0lo, o[q][0]);
            o[q][1] = __builtin_elementwise_fma(p0v, v0hi, o[q][1]);
            o[q][0] = __builtin_elementwise_fma(p1v, v1lo, o[q][0]);
            o[q][1] = __builtin_elementwise_fma(p1v, v1hi, o[q][1]);
            o[q][0] = __builtin_elementwise_fma(p2v, v2lo, o[q][0]);
            o[q][1] = __builtin_elementwise_fma(p2v, v2hi, o[q][1]);
            o[q][0] = __builtin_elementwise_fma(p3v, v3lo, o[q][0]);
            o[q][1] = __builtin_elementwise_fma(p3v, v3hi, o[q][1]);
        }
    }
    #pragma unroll
    for (int q = 0; q < QB; ++q) {
        *(v2f*)&accbuf[kq][q][lane][0] = o[q][0];
        *(v2f*)&accbuf[kq][q][lane][2] = o[q][1];
    }
    __syncthreads();

    // reduce k-quarters: thread = (q = tid>>6, c4 = tid&63)
    {
        const int q = tid >> 6, c4 = tid & 63;
        float4 s0 = *(const float4*)&accbuf[0][q][c4][0];
        float4 s1 = *(const float4*)&accbuf[1][q][c4][0];
        float4 s2 = *(const float4*)&accbuf[2][q][c4][0];
        float4 s3 = *(const float4*)&accbuf[3][q][c4][0];
        float inv = __builtin_amdgcn_rcpf(rowsum[q]);
        float4 r;
        r.x = (s0.x + s1.x + s2.x + s3.x) * inv;
        r.y = (s0.y + s1.y + s2.y + s3.y) * inv;
        r.z = (s0.z + s1.z + s2.z + s3.z) * inv;
        r.w = (s0.w + s1.w + s2.w + s3.w) * inv;
        *(float4*)(out + (b * TQ + qg * QB + q) * DV + vh * 256 + c4 * 4) = r;
    }
}

extern "C" void kernel_launch(void* const* d_in, const int* in_sizes, int n_in,
                              void* d_out, int out_size, void* d_ws, size_t ws_size,
                              hipStream_t stream)
{
    const float* queries = (const float*)d_in[0];
    const float* keys    = (const float*)d_in[1];
    const float* values  = (const float*)d_in[2];
    const float* Wq      = (const float*)d_in[3];
    const float* Wk      = (const float*)d_in[4];
    const float* wv      = (const float*)d_in[5];
    float* out     = (float*)d_out;
    float* qpc     = (float*)d_ws;                    // (B*TQ, H)        2 MB
    float* kpc4    = qpc + B * TQ * H;                // (B, H/4, TK, 4)  2 MB
    float* partial = kpc4 + B * H * TK;               // (B*64*NH, 4, TK) 4 MB

    dim3 gproj(B * TQ / 64, H / 64, 2);
    proj_kernel<<<gproj, 256, 0, stream>>>(queries, keys, Wq, Wk, qpc, kpc4);
    score_kernel<<<B * (TQ / QB) * NH, 256, 0, stream>>>(qpc, kpc4, wv, partial);
    pv_kernel<<<B * (TQ / QB) * 2, 256, 0, stream>>>(partial, values, out);
}

// Round 6
// 69.254 us; speedup vs baseline: 1.0605x; 1.0589x over previous
//
#include <hip/hip_runtime.h>

typedef float v2f __attribute__((ext_vector_type(2)));

namespace {
constexpr int B   = 8;
constexpr int TQ  = 256;
constexpr int TK  = 256;
constexpr int DQK = 512;
constexpr int DV  = 512;
constexpr int H   = 256;
constexpr int QB  = 4;           // q rows per attn block
constexpr int HS  = H / 2;       // h-half per thread-half
constexpr float C2LOG2E = 2.8853900817779268f; // 2*log2(e)
constexpr float LOG2E   = 1.4426950408889634f;
} // namespace

// Fused projections, 4x4 register tile + global->reg prefetch:
//  z==0: qpc[b*TQ+q][h]       = (queries @ Wq)[row][h] * 2log2e
//  z==1: kpc4[b][h/4][k][h&3] = (keys    @ Wk)[row][h] * 2log2e
__global__ __launch_bounds__(256)
void proj_kernel(const float* __restrict__ Q, const float* __restrict__ Kin,
                 const float* __restrict__ Wq, const float* __restrict__ Wk,
                 float* __restrict__ qpc, float* __restrict__ kpc4)
{
    constexpr int BM = 64, BN = 64, BK = 16;
    __shared__ float As[BK][BM];   // A tile stored transposed (k-major)
    __shared__ float Bs[BK][BN];

    const bool kside = (blockIdx.z == 1);
    const float* A = kside ? Kin : Q;
    const float* W = kside ? Wk  : Wq;
    const int m0 = blockIdx.x * BM;
    const int n0 = blockIdx.y * BN;
    const int tid = threadIdx.x;
    const int tx = tid & 15;        // col group (4 cols)
    const int ty = tid >> 4;        // row group (4 rows)
    const int ar = tid >> 2, ac4 = (tid & 3) * 4;   // A load: row ar, k ac4..+3
    const int br = tid >> 4, bc4 = (tid & 15) * 4;  // B load: k br, col bc4..+3

    // prefetch first tiles into registers
    float4 av = *(const float4*)(A + (m0 + ar) * DQK + ac4);
    float4 bv = *(const float4*)(W + br * H + n0 + bc4);

    v2f acc[4][2] = {};
    for (int k0 = 0; k0 < DQK; k0 += BK) {
        __syncthreads();   // previous iteration's LDS reads complete
        As[ac4 + 0][ar] = av.x;
        As[ac4 + 1][ar] = av.y;
        As[ac4 + 2][ar] = av.z;
        As[ac4 + 3][ar] = av.w;
        *(float4*)&Bs[br][bc4] = bv;
        __syncthreads();
        if (k0 + BK < DQK) {   // prefetch next tiles (hidden under fma chain)
            av = *(const float4*)(A + (m0 + ar) * DQK + k0 + BK + ac4);
            bv = *(const float4*)(W + (k0 + BK + br) * H + n0 + bc4);
        }
        #pragma unroll
        for (int kk = 0; kk < BK; ++kk) {
            float4 a4 = *(const float4*)&As[kk][ty * 4];
            float4 b4 = *(const float4*)&Bs[kk][tx * 4];
            v2f blo = {b4.x, b4.y}, bhi = {b4.z, b4.w};
            v2f ax = {a4.x, a4.x}, ay = {a4.y, a4.y};
            v2f az = {a4.z, a4.z}, aw = {a4.w, a4.w};
            acc[0][0] = __builtin_elementwise_fma(ax, blo, acc[0][0]);
            acc[0][1] = __builtin_elementwise_fma(ax, bhi, acc[0][1]);
            acc[1][0] = __builtin_elementwise_fma(ay, blo, acc[1][0]);
            acc[1][1] = __builtin_elementwise_fma(ay, bhi, acc[1][1]);
            acc[2][0] = __builtin_elementwise_fma(az, blo, acc[2][0]);
            acc[2][1] = __builtin_elementwise_fma(az, bhi, acc[2][1]);
            acc[3][0] = __builtin_elementwise_fma(aw, blo, acc[3][0]);
            acc[3][1] = __builtin_elementwise_fma(aw, bhi, acc[3][1]);
        }
    }

    if (!kside) {
        #pragma unroll
        for (int i = 0; i < 4; ++i) {
            float4 r;
            r.x = acc[i][0].x * C2LOG2E;
            r.y = acc[i][0].y * C2LOG2E;
            r.z = acc[i][1].x * C2LOG2E;
            r.w = acc[i][1].y * C2LOG2E;
            *(float4*)(qpc + (m0 + ty * 4 + i) * H + n0 + tx * 4) = r;
        }
    } else {
        const int h = n0 + tx * 4;     // multiple of 4
        #pragma unroll
        for (int i = 0; i < 4; ++i) {
            const int row = m0 + ty * 4 + i;   // = b*256 + k
            const int bb = row >> 8, kk = row & 255;
            float4 r;
            r.x = acc[i][0].x * C2LOG2E;
            r.y = acc[i][0].y * C2LOG2E;
            r.z = acc[i][1].x * C2LOG2E;
            r.w = acc[i][1].y * C2LOG2E;
            *(float4*)(kpc4 + ((bb * (H / 4) + (h >> 2)) * TK + kk) * 4) = r;
        }
    }
}

// Fused scores + softmax + PV. Block = (b, qgroup of 4), 512 threads.
// Thread (k = tid&255, half = tid>>8). Score phase: half splits H (float4
// kpc4 loads). PV phase: half splits K. LDS partial reduction for both.
// logits = -2 * sum_h wv[h] * rcp(exp2(qpc+kpc) + 1)   (constant term cancels)
__global__ __launch_bounds__(512)
void attn_kernel(const float* __restrict__ qpc, const float* __restrict__ kpc4,
                 const float* __restrict__ wv, const float* __restrict__ values,
                 float* __restrict__ out)
{
    __shared__ float qlds[QB][H];        // 4 KB
    __shared__ float wlds[H];            // 1 KB
    __shared__ float elds[QB][TK];       // 4 KB
    __shared__ float accbuf[2][QB][DV];  // 16 KB (score phase uses [..][..][0:TK])
    __shared__ float rowsum[QB];

    const int b    = blockIdx.x / (TQ / QB);
    const int q0   = (blockIdx.x % (TQ / QB)) * QB;
    const int tid  = threadIdx.x;
    const int k    = tid & 255;
    const int half = tid >> 8;

    for (int i = tid; i < QB * H; i += 512)
        qlds[i >> 8][i & 255] = qpc[(b * TQ + q0 + (i >> 8)) * H + (i & 255)];
    if (tid < H) wlds[tid] = wv[tid];
    __syncthreads();

    // ---- score phase: h-half per thread-half, float4 k loads ----
    const int h0 = half * HS;
    const float4* kc = (const float4*)kpc4 + (b * (H / 4) + (h0 >> 2)) * TK + k;
    float acc[QB] = {};
    #pragma unroll 4
    for (int h4 = 0; h4 < HS / 4; ++h4) {
        float4 kv = kc[h4 * TK];
        float4 w4 = *(const float4*)&wlds[h0 + h4 * 4];
        #pragma unroll
        for (int q = 0; q < QB; ++q) {
            float4 q4 = *(const float4*)&qlds[q][h0 + h4 * 4];
            acc[q] = fmaf(w4.x, __builtin_amdgcn_rcpf(__builtin_amdgcn_exp2f(q4.x + kv.x) + 1.0f), acc[q]);
            acc[q] = fmaf(w4.y, __builtin_amdgcn_rcpf(__builtin_amdgcn_exp2f(q4.y + kv.y) + 1.0f), acc[q]);
            acc[q] = fmaf(w4.z, __builtin_amdgcn_rcpf(__builtin_amdgcn_exp2f(q4.z + kv.z) + 1.0f), acc[q]);
            acc[q] = fmaf(w4.w, __builtin_amdgcn_rcpf(__builtin_amdgcn_exp2f(q4.w + kv.w) + 1.0f), acc[q]);
        }
    }
    #pragma unroll
    for (int q = 0; q < QB; ++q) accbuf[half][q][k] = acc[q];
    __syncthreads();

    // ---- combine halves -> logits ----
    for (int i = tid; i < QB * TK; i += 512) {
        const int q = i >> 8, kk = i & 255;
        elds[q][kk] = -2.0f * (accbuf[0][q][kk] + accbuf[1][q][kk]);
    }
    __syncthreads();

    // ---- softmax: waves 0-3 and 4-7 redundantly handle rows 0-3 ----
    // (redundant duplicate keeps barriers uniform across all 512 threads;
    //  both copies compute and write identical values)
    {
        const int q = (tid >> 6) & 3, lane = tid & 63;
        float4 v = *(const float4*)&elds[q][lane * 4];
        float m = fmaxf(fmaxf(v.x, v.y), fmaxf(v.z, v.w));
        #pragma unroll
        for (int off = 1; off < 64; off <<= 1)
            m = fmaxf(m, __shfl_xor(m, off));
        float e0 = __builtin_amdgcn_exp2f((v.x - m) * LOG2E);
        float e1 = __builtin_amdgcn_exp2f((v.y - m) * LOG2E);
        float e2 = __builtin_amdgcn_exp2f((v.z - m) * LOG2E);
        float e3 = __builtin_amdgcn_exp2f((v.w - m) * LOG2E);
        float s = (e0 + e1) + (e2 + e3);
        #pragma unroll
        for (int off = 1; off < 64; off <<= 1)
            s += __shfl_xor(s, off);
        __syncthreads();   // all logits read before overwrite
        *(float4*)&elds[q][lane * 4] = make_float4(e0, e1, e2, e3);
        if (lane == 0) rowsum[q] = s;
    }
    __syncthreads();

    // ---- PV: half k-range per thread-half; thread owns cols k, k+256 ----
    float o[QB][2] = {};
    const float* vb = values + b * TK * DV;
    const int kbeg = half * (TK / 2);
    for (int kk0 = kbeg; kk0 < kbeg + TK / 2; kk0 += 4) {
        float v0a = vb[(kk0 + 0) * DV + k], v0b = vb[(kk0 + 0) * DV + k + 256];
        float v1a = vb[(kk0 + 1) * DV + k], v1b = vb[(kk0 + 1) * DV + k + 256];
        float v2a = vb[(kk0 + 2) * DV + k], v2b = vb[(kk0 + 2) * DV + k + 256];
        float v3a = vb[(kk0 + 3) * DV + k], v3b = vb[(kk0 + 3) * DV + k + 256];
        #pragma unroll
        for (int q = 0; q < QB; ++q) {
            float4 p = *(const float4*)&elds[q][kk0];
            o[q][0] = fmaf(p.x, v0a, o[q][0]);
            o[q][1] = fmaf(p.x, v0b, o[q][1]);
            o[q][0] = fmaf(p.y, v1a, o[q][0]);
            o[q][1] = fmaf(p.y, v1b, o[q][1]);
            o[q][0] = fmaf(p.z, v2a, o[q][0]);
            o[q][1] = fmaf(p.z, v2b, o[q][1]);
            o[q][0] = fmaf(p.w, v3a, o[q][0]);
            o[q][1] = fmaf(p.w, v3b, o[q][1]);
        }
    }
    #pragma unroll
    for (int q = 0; q < QB; ++q) {
        accbuf[half][q][k]       = o[q][0];
        accbuf[half][q][k + 256] = o[q][1];
    }
    __syncthreads();

    for (int i = tid; i < QB * DV; i += 512) {
        const int q = i >> 9, c = i & 511;
        float val = (accbuf[0][q][c] + accbuf[1][q][c]) *
                    __builtin_amdgcn_rcpf(rowsum[q]);
        out[(b * TQ + q0 + q) * DV + c] = val;
    }
}

extern "C" void kernel_launch(void* const* d_in, const int* in_sizes, int n_in,
                              void* d_out, int out_size, void* d_ws, size_t ws_size,
                              hipStream_t stream)
{
    const float* queries = (const float*)d_in[0];
    const float* keys    = (const float*)d_in[1];
    const float* values  = (const float*)d_in[2];
    const float* Wq      = (const float*)d_in[3];
    const float* Wk      = (const float*)d_in[4];
    const float* wv      = (const float*)d_in[5];
    float* out     = (float*)d_out;
    float* qpc     = (float*)d_ws;                    // (B*TQ, H)        2 MB
    float* kpc4    = qpc + B * TQ * H;                // (B, H/4, TK, 4)  2 MB

    dim3 gproj(B * TQ / 64, H / 64, 2);
    proj_kernel<<<gproj, 256, 0, stream>>>(queries, keys, Wq, Wk, qpc, kpc4);
    attn_kernel<<<B * (TQ / QB), 512, 0, stream>>>(qpc, kpc4, wv, values, out);
}

// Round 7
// 68.222 us; speedup vs baseline: 1.0766x; 1.0151x over previous
//
#include <hip/hip_runtime.h>

typedef float v2f __attribute__((ext_vector_type(2)));

namespace {
constexpr int B   = 8;
constexpr int TQ  = 256;
constexpr int TK  = 256;
constexpr int DQK = 512;
constexpr int DV  = 512;
constexpr int H   = 256;
constexpr int QB  = 8;           // q rows per attn block
constexpr float C2LOG2E = 2.8853900817779268f; // 2*log2(e)
constexpr float LOG2E   = 1.4426950408889634f;
} // namespace

// Fused projections, 4x4 register tile + global->reg prefetch:
//  z==0: qpc[b*TQ+q][h]       = (queries @ Wq)[row][h] * 2log2e
//  z==1: kpc4[b][h/4][k][h&3] = (keys    @ Wk)[row][h] * 2log2e
__global__ __launch_bounds__(256)
void proj_kernel(const float* __restrict__ Q, const float* __restrict__ Kin,
                 const float* __restrict__ Wq, const float* __restrict__ Wk,
                 float* __restrict__ qpc, float* __restrict__ kpc4)
{
    constexpr int BM = 64, BN = 64, BK = 16;
    __shared__ float As[BK][BM];   // A tile stored transposed (k-major)
    __shared__ float Bs[BK][BN];

    const bool kside = (blockIdx.z == 1);
    const float* A = kside ? Kin : Q;
    const float* W = kside ? Wk  : Wq;
    const int m0 = blockIdx.x * BM;
    const int n0 = blockIdx.y * BN;
    const int tid = threadIdx.x;
    const int tx = tid & 15;        // col group (4 cols)
    const int ty = tid >> 4;        // row group (4 rows)
    const int ar = tid >> 2, ac4 = (tid & 3) * 4;   // A load: row ar, k ac4..+3
    const int br = tid >> 4, bc4 = (tid & 15) * 4;  // B load: k br, col bc4..+3

    // prefetch first tiles into registers
    float4 av = *(const float4*)(A + (m0 + ar) * DQK + ac4);
    float4 bv = *(const float4*)(W + br * H + n0 + bc4);

    v2f acc[4][2] = {};
    for (int k0 = 0; k0 < DQK; k0 += BK) {
        __syncthreads();   // previous iteration's LDS reads complete
        As[ac4 + 0][ar] = av.x;
        As[ac4 + 1][ar] = av.y;
        As[ac4 + 2][ar] = av.z;
        As[ac4 + 3][ar] = av.w;
        *(float4*)&Bs[br][bc4] = bv;
        __syncthreads();
        if (k0 + BK < DQK) {   // prefetch next tiles (hidden under fma chain)
            av = *(const float4*)(A + (m0 + ar) * DQK + k0 + BK + ac4);
            bv = *(const float4*)(W + (k0 + BK + br) * H + n0 + bc4);
        }
        #pragma unroll
        for (int kk = 0; kk < BK; ++kk) {
            float4 a4 = *(const float4*)&As[kk][ty * 4];
            float4 b4 = *(const float4*)&Bs[kk][tx * 4];
            v2f blo = {b4.x, b4.y}, bhi = {b4.z, b4.w};
            v2f ax = {a4.x, a4.x}, ay = {a4.y, a4.y};
            v2f az = {a4.z, a4.z}, aw = {a4.w, a4.w};
            acc[0][0] = __builtin_elementwise_fma(ax, blo, acc[0][0]);
            acc[0][1] = __builtin_elementwise_fma(ax, bhi, acc[0][1]);
            acc[1][0] = __builtin_elementwise_fma(ay, blo, acc[1][0]);
            acc[1][1] = __builtin_elementwise_fma(ay, bhi, acc[1][1]);
            acc[2][0] = __builtin_elementwise_fma(az, blo, acc[2][0]);
            acc[2][1] = __builtin_elementwise_fma(az, bhi, acc[2][1]);
            acc[3][0] = __builtin_elementwise_fma(aw, blo, acc[3][0]);
            acc[3][1] = __builtin_elementwise_fma(aw, bhi, acc[3][1]);
        }
    }

    if (!kside) {
        #pragma unroll
        for (int i = 0; i < 4; ++i) {
            float4 r;
            r.x = acc[i][0].x * C2LOG2E;
            r.y = acc[i][0].y * C2LOG2E;
            r.z = acc[i][1].x * C2LOG2E;
            r.w = acc[i][1].y * C2LOG2E;
            *(float4*)(qpc + (m0 + ty * 4 + i) * H + n0 + tx * 4) = r;
        }
    } else {
        const int h = n0 + tx * 4;     // multiple of 4
        #pragma unroll
        for (int i = 0; i < 4; ++i) {
            const int row = m0 + ty * 4 + i;   // = b*256 + k
            const int bb = row >> 8, kk = row & 255;
            float4 r;
            r.x = acc[i][0].x * C2LOG2E;
            r.y = acc[i][0].y * C2LOG2E;
            r.z = acc[i][1].x * C2LOG2E;
            r.w = acc[i][1].y * C2LOG2E;
            *(float4*)(kpc4 + ((bb * (H / 4) + (h >> 2)) * TK + kk) * 4) = r;
        }
    }
}

// Fused scores + softmax + PV. Block = (b, qgroup of 8), 1024 threads.
// Score: thread (k = tid&255, quarter = tid>>8 owns 64 h), packed over q-pairs.
// PV: thread (c = tid&511, khalf = tid>>9 owns 128 k).
// logits = -2 * sum_h wv[h] * rcp(exp2(qpc+kpc) + 1)   (constant term cancels)
__global__ __launch_bounds__(1024)
void attn_kernel(const float* __restrict__ qpc, const float* __restrict__ kpc4,
                 const float* __restrict__ wv, const float* __restrict__ values,
                 float* __restrict__ out)
{
    __shared__ float qlds[H][QB];      // 8 KB  [h][q] (q-major for v2f pair reads)
    __shared__ float wlds[H];          // 1 KB
    __shared__ float elds[QB][TK];     // 8 KB
    __shared__ float rowsum[QB];
    __shared__ float accflat[8192];    // 32 KB: score [4][8][256] / pv [2][8][512]

    const int b   = blockIdx.x >> 5;           // 32 q-groups per batch
    const int q0  = (blockIdx.x & 31) * QB;
    const int tid = threadIdx.x;

    for (int i = tid; i < QB * H; i += 1024) {
        const int h = i >> 3, q = i & 7;
        qlds[h][q] = qpc[(b * TQ + q0 + q) * H + h];
    }
    if (tid < H) wlds[tid] = wv[tid];
    __syncthreads();

    // ---- score: quarter handles h in [h0, h0+64); packed over q-pairs ----
    {
        const int k = tid & 255;
        const int quarter = tid >> 8;
        const int h0 = quarter * 64;
        const float4* kc = (const float4*)kpc4 + (b * (H / 4) + (h0 >> 2)) * TK + k;
        v2f acc2[4] = {};
        #pragma unroll 2
        for (int h4 = 0; h4 < 16; ++h4) {
            float4 kv = kc[h4 * TK];
            float4 w4 = *(const float4*)&wlds[h0 + h4 * 4];
            #pragma unroll
            for (int j = 0; j < 4; ++j) {
                const int h = h0 + h4 * 4 + j;
                const float kvj = (j == 0) ? kv.x : (j == 1) ? kv.y : (j == 2) ? kv.z : kv.w;
                const float wj  = (j == 0) ? w4.x : (j == 1) ? w4.y : (j == 2) ? w4.z : w4.w;
                v2f kv2 = {kvj, kvj};
                v2f w2  = {wj, wj};
                float4 qa = *(const float4*)&qlds[h][0];
                float4 qb = *(const float4*)&qlds[h][4];
                v2f qp[4] = {{qa.x, qa.y}, {qa.z, qa.w}, {qb.x, qb.y}, {qb.z, qb.w}};
                #pragma unroll
                for (int p = 0; p < 4; ++p) {
                    v2f t = qp[p] + kv2;                       // v_pk_add_f32
                    v2f e;
                    e.x = __builtin_amdgcn_exp2f(t.x);
                    e.y = __builtin_amdgcn_exp2f(t.y);
                    v2f d = e + (v2f){1.0f, 1.0f};             // v_pk_add_f32
                    v2f r;
                    r.x = __builtin_amdgcn_rcpf(d.x);
                    r.y = __builtin_amdgcn_rcpf(d.y);
                    acc2[p] = __builtin_elementwise_fma(w2, r, acc2[p]);  // v_pk_fma_f32
                }
            }
        }
        #pragma unroll
        for (int p = 0; p < 4; ++p) {
            accflat[(quarter * 8 + 2 * p    ) * 256 + k] = acc2[p].x;
            accflat[(quarter * 8 + 2 * p + 1) * 256 + k] = acc2[p].y;
        }
    }
    __syncthreads();

    // ---- combine quarters -> logits ----
    for (int i = tid; i < QB * TK; i += 1024) {
        const int q = i >> 8, kk = i & 255;
        float s = accflat[q * 256 + kk]          + accflat[(8 + q) * 256 + kk]
                + accflat[(16 + q) * 256 + kk]   + accflat[(24 + q) * 256 + kk];
        elds[q][kk] = -2.0f * s;
    }
    __syncthreads();

    // ---- softmax: 16 waves cover 8 rows twice; only waves 0-7 write ----
    {
        const int q = (tid >> 6) & 7, lane = tid & 63;
        float4 v = *(const float4*)&elds[q][lane * 4];
        float m = fmaxf(fmaxf(v.x, v.y), fmaxf(v.z, v.w));
        #pragma unroll
        for (int off = 1; off < 64; off <<= 1)
            m = fmaxf(m, __shfl_xor(m, off));
        float e0 = __builtin_amdgcn_exp2f((v.x - m) * LOG2E);
        float e1 = __builtin_amdgcn_exp2f((v.y - m) * LOG2E);
        float e2 = __builtin_amdgcn_exp2f((v.z - m) * LOG2E);
        float e3 = __builtin_amdgcn_exp2f((v.w - m) * LOG2E);
        float s = (e0 + e1) + (e2 + e3);
        #pragma unroll
        for (int off = 1; off < 64; off <<= 1)
            s += __shfl_xor(s, off);
        __syncthreads();    // all logits consumed before overwrite
        if (tid < 512) {
            *(float4*)&elds[q][lane * 4] = make_float4(e0, e1, e2, e3);
            if (lane == 0) rowsum[q] = s;
        }
    }
    __syncthreads();

    // ---- PV: khalf = tid>>9 owns 128 k; thread owns col c = tid&511 ----
    {
        const int kh = tid >> 9, c = tid & 511;
        const float* vb = values + (b * TK + kh * 128) * DV + c;
        float o[QB] = {};
        for (int kk = 0; kk < 128; ++kk) {
            float v = vb[kk * DV];
            const int kc = kh * 128 + kk;
            #pragma unroll
            for (int q = 0; q < QB; ++q)
                o[q] = fmaf(elds[q][kc], v, o[q]);
        }
        #pragma unroll
        for (int q = 0; q < QB; ++q)
            accflat[(kh * 8 + q) * 512 + c] = o[q];
    }
    __syncthreads();

    for (int i = tid; i < QB * DV; i += 1024) {
        const int q = i >> 9, c = i & 511;
        float val = (accflat[q * 512 + c] + accflat[(8 + q) * 512 + c]) *
                    __builtin_amdgcn_rcpf(rowsum[q]);
        out[(b * TQ + q0 + q) * DV + c] = val;
    }
}

extern "C" void kernel_launch(void* const* d_in, const int* in_sizes, int n_in,
                              void* d_out, int out_size, void* d_ws, size_t ws_size,
                              hipStream_t stream)
{
    const float* queries = (const float*)d_in[0];
    const float* keys    = (const float*)d_in[1];
    const float* values  = (const float*)d_in[2];
    const float* Wq      = (const float*)d_in[3];
    const float* Wk      = (const float*)d_in[4];
    const float* wv      = (const float*)d_in[5];
    float* out  = (float*)d_out;
    float* qpc  = (float*)d_ws;                    // (B*TQ, H)        2 MB
    float* kpc4 = qpc + B * TQ * H;                // (B, H/4, TK, 4)  2 MB

    dim3 gproj(B * TQ / 64, H / 64, 2);
    proj_kernel<<<gproj, 256, 0, stream>>>(queries, keys, Wq, Wk, qpc, kpc4);
    attn_kernel<<<B * (TQ / QB), 1024, 0, stream>>>(qpc, kpc4, wv, values, out);
}

// Round 8
// 66.955 us; speedup vs baseline: 1.0969x; 1.0189x over previous
//
#include <hip/hip_runtime.h>

typedef float v2f __attribute__((ext_vector_type(2)));

namespace {
constexpr int B   = 8;
constexpr int TQ  = 256;
constexpr int TK  = 256;
constexpr int DQK = 512;
constexpr int DV  = 512;
constexpr int H   = 256;
constexpr int QB  = 4;           // q rows per attn block
constexpr float C2LOG2E = 2.8853900817779268f;  // 2*log2(e)
constexpr float NEG2LOG2E = -2.8853900817779268f;
} // namespace

// Fused projections, 4x4 register tile + global->reg prefetch:
//  z==0: qpc[b*TQ+q][h]       = (queries @ Wq)[row][h] * 2log2e
//  z==1: kpc4[b][h/4][k][h&3] = (keys    @ Wk)[row][h] * 2log2e
__global__ __launch_bounds__(256)
void proj_kernel(const float* __restrict__ Q, const float* __restrict__ Kin,
                 const float* __restrict__ Wq, const float* __restrict__ Wk,
                 float* __restrict__ qpc, float* __restrict__ kpc4)
{
    constexpr int BM = 64, BN = 64, BK = 16;
    __shared__ float As[BK][BM];   // A tile stored transposed (k-major)
    __shared__ float Bs[BK][BN];

    const bool kside = (blockIdx.z == 1);
    const float* A = kside ? Kin : Q;
    const float* W = kside ? Wk  : Wq;
    const int m0 = blockIdx.x * BM;
    const int n0 = blockIdx.y * BN;
    const int tid = threadIdx.x;
    const int tx = tid & 15;        // col group (4 cols)
    const int ty = tid >> 4;        // row group (4 rows)
    const int ar = tid >> 2, ac4 = (tid & 3) * 4;   // A load: row ar, k ac4..+3
    const int br = tid >> 4, bc4 = (tid & 15) * 4;  // B load: k br, col bc4..+3

    // prefetch first tiles into registers
    float4 av = *(const float4*)(A + (m0 + ar) * DQK + ac4);
    float4 bv = *(const float4*)(W + br * H + n0 + bc4);

    v2f acc[4][2] = {};
    for (int k0 = 0; k0 < DQK; k0 += BK) {
        __syncthreads();   // previous iteration's LDS reads complete
        As[ac4 + 0][ar] = av.x;
        As[ac4 + 1][ar] = av.y;
        As[ac4 + 2][ar] = av.z;
        As[ac4 + 3][ar] = av.w;
        *(float4*)&Bs[br][bc4] = bv;
        __syncthreads();
        if (k0 + BK < DQK) {   // prefetch next tiles (hidden under fma chain)
            av = *(const float4*)(A + (m0 + ar) * DQK + k0 + BK + ac4);
            bv = *(const float4*)(W + (k0 + BK + br) * H + n0 + bc4);
        }
        #pragma unroll
        for (int kk = 0; kk < BK; ++kk) {
            float4 a4 = *(const float4*)&As[kk][ty * 4];
            float4 b4 = *(const float4*)&Bs[kk][tx * 4];
            v2f blo = {b4.x, b4.y}, bhi = {b4.z, b4.w};
            v2f ax = {a4.x, a4.x}, ay = {a4.y, a4.y};
            v2f az = {a4.z, a4.z}, aw = {a4.w, a4.w};
            acc[0][0] = __builtin_elementwise_fma(ax, blo, acc[0][0]);
            acc[0][1] = __builtin_elementwise_fma(ax, bhi, acc[0][1]);
            acc[1][0] = __builtin_elementwise_fma(ay, blo, acc[1][0]);
            acc[1][1] = __builtin_elementwise_fma(ay, bhi, acc[1][1]);
            acc[2][0] = __builtin_elementwise_fma(az, blo, acc[2][0]);
            acc[2][1] = __builtin_elementwise_fma(az, bhi, acc[2][1]);
            acc[3][0] = __builtin_elementwise_fma(aw, blo, acc[3][0]);
            acc[3][1] = __builtin_elementwise_fma(aw, bhi, acc[3][1]);
        }
    }

    if (!kside) {
        #pragma unroll
        for (int i = 0; i < 4; ++i) {
            float4 r;
            r.x = acc[i][0].x * C2LOG2E;
            r.y = acc[i][0].y * C2LOG2E;
            r.z = acc[i][1].x * C2LOG2E;
            r.w = acc[i][1].y * C2LOG2E;
            *(float4*)(qpc + (m0 + ty * 4 + i) * H + n0 + tx * 4) = r;
        }
    } else {
        const int h = n0 + tx * 4;     // multiple of 4
        #pragma unroll
        for (int i = 0; i < 4; ++i) {
            const int row = m0 + ty * 4 + i;   // = b*256 + k
            const int bb = row >> 8, kk = row & 255;
            float4 r;
            r.x = acc[i][0].x * C2LOG2E;
            r.y = acc[i][0].y * C2LOG2E;
            r.z = acc[i][1].x * C2LOG2E;
            r.w = acc[i][1].y * C2LOG2E;
            *(float4*)(kpc4 + ((bb * (H / 4) + (h >> 2)) * TK + kk) * 4) = r;
        }
    }
}

// Fused scores + softmax + PV. Block = (b, qgroup of 4), 512 threads, grid 512
// (2 blocks/CU so barrier drains overlap with the co-resident block).
// Score: thread (k = tid&255, half = tid>>8 owns 128 h), packed over q-pairs.
// Softmax WITHOUT max-subtraction: logits bounded (|logit| <= 2*log2e*sum|wv|
// ~ 37 exp2-units -> max e-value ~1.6e11, row sums < 4.2e13, all safe in fp32).
// PV: thread (c = tid&255 owns cols c,c+256; kh = tid>>8 owns 128 k).
__global__ __launch_bounds__(512)
void attn_kernel(const float* __restrict__ qpc, const float* __restrict__ kpc4,
                 const float* __restrict__ wv, const float* __restrict__ values,
                 float* __restrict__ out)
{
    __shared__ float qlds[H][QB];        // 4 KB [h][q]
    __shared__ float wlds[H];            // 1 KB
    __shared__ float elds[QB][TK];       // 4 KB
    __shared__ float rowsum[QB];
    __shared__ float accbuf[2][QB][DV];  // 16 KB (score uses [..][..][0:256])

    const int b   = blockIdx.x >> 6;     // 64 q-groups per batch
    const int q0  = (blockIdx.x & 63) * QB;
    const int tid = threadIdx.x;

    for (int i = tid; i < QB * H; i += 512) {
        const int h = i >> 2, q = i & 3;
        qlds[h][q] = qpc[(b * TQ + q0 + q) * H + h];
    }
    if (tid < H) wlds[tid] = wv[tid];
    __syncthreads();

    // ---- score: half owns h in [h0, h0+128); packed over q-pairs ----
    {
        const int k = tid & 255;
        const int half = tid >> 8;
        const int h0 = half * 128;
        const float4* kc = (const float4*)kpc4 + (b * (H / 4) + (h0 >> 2)) * TK + k;
        v2f a01 = {0.f, 0.f}, a23 = {0.f, 0.f};
        #pragma unroll 4
        for (int h4 = 0; h4 < 32; ++h4) {
            float4 kv = kc[h4 * TK];
            float4 w4 = *(const float4*)&wlds[h0 + h4 * 4];
            #pragma unroll
            for (int j = 0; j < 4; ++j) {
                const int h = h0 + h4 * 4 + j;
                const float kvj = (j == 0) ? kv.x : (j == 1) ? kv.y : (j == 2) ? kv.z : kv.w;
                const float wj  = (j == 0) ? w4.x : (j == 1) ? w4.y : (j == 2) ? w4.z : w4.w;
                float4 qa = *(const float4*)&qlds[h][0];   // broadcast ds_read_b128
                v2f kv2 = {kvj, kvj}, w2 = {wj, wj};
                v2f q01 = {qa.x, qa.y}, q23 = {qa.z, qa.w};
                v2f t0 = q01 + kv2;                        // v_pk_add_f32
                v2f t1 = q23 + kv2;
                v2f e0, e1;
                e0.x = __builtin_amdgcn_exp2f(t0.x);
                e0.y = __builtin_amdgcn_exp2f(t0.y);
                e1.x = __builtin_amdgcn_exp2f(t1.x);
                e1.y = __builtin_amdgcn_exp2f(t1.y);
                v2f d0 = e0 + (v2f){1.0f, 1.0f};
                v2f d1 = e1 + (v2f){1.0f, 1.0f};
                v2f r0, r1;
                r0.x = __builtin_amdgcn_rcpf(d0.x);
                r0.y = __builtin_amdgcn_rcpf(d0.y);
                r1.x = __builtin_amdgcn_rcpf(d1.x);
                r1.y = __builtin_amdgcn_rcpf(d1.y);
                a01 = __builtin_elementwise_fma(w2, r0, a01);
                a23 = __builtin_elementwise_fma(w2, r1, a23);
            }
        }
        accbuf[half][0][k] = a01.x;
        accbuf[half][1][k] = a01.y;
        accbuf[half][2][k] = a23.x;
        accbuf[half][3][k] = a23.y;
    }
    __syncthreads();

    // ---- combine halves -> e = exp2(-2log2e * acc)  (no max needed) ----
    for (int i = tid; i < QB * TK; i += 512) {
        const int q = i >> 8, kk = i & 255;
        float s = accbuf[0][q][kk] + accbuf[1][q][kk];
        elds[q][kk] = __builtin_amdgcn_exp2f(s * NEG2LOG2E);
    }
    __syncthreads();

    // ---- rowsum: wave w reduces row (w&3); waves 4-7 duplicate harmlessly --
    {
        const int q = (tid >> 6) & 3, lane = tid & 63;
        float4 v = *(const float4*)&elds[q][lane * 4];
        float s = (v.x + v.y) + (v.z + v.w);
        #pragma unroll
        for (int off = 1; off < 64; off <<= 1)
            s += __shfl_xor(s, off);
        if (tid < 256 && lane == 0) rowsum[q] = s;
    }
    __syncthreads();

    // ---- PV: kh owns 128 k; thread owns cols c, c+256 (packed pair) ----
    {
        const int c = tid & 255, kh = tid >> 8;
        const float* vb = values + (b * TK + kh * 128) * DV;
        v2f o[QB] = {};
        for (int kk = 0; kk < 128; ++kk) {
            v2f vv = {vb[kk * DV + c], vb[kk * DV + c + 256]};
            const int kc = kh * 128 + kk;
            #pragma unroll
            for (int q = 0; q < QB; ++q) {
                float e = elds[q][kc];                 // broadcast
                v2f e2 = {e, e};
                o[q] = __builtin_elementwise_fma(e2, vv, o[q]);   // v_pk_fma_f32
            }
        }
        #pragma unroll
        for (int q = 0; q < QB; ++q) {
            accbuf[kh][q][c]       = o[q].x;
            accbuf[kh][q][c + 256] = o[q].y;
        }
    }
    __syncthreads();

    for (int i = tid; i < QB * DV; i += 512) {
        const int q = i >> 9, c = i & 511;
        float val = (accbuf[0][q][c] + accbuf[1][q][c]) *
                    __builtin_amdgcn_rcpf(rowsum[q]);
        out[(b * TQ + q0 + q) * DV + c] = val;
    }
}

extern "C" void kernel_launch(void* const* d_in, const int* in_sizes, int n_in,
                              void* d_out, int out_size, void* d_ws, size_t ws_size,
                              hipStream_t stream)
{
    const float* queries = (const float*)d_in[0];
    const float* keys    = (const float*)d_in[1];
    const float* values  = (const float*)d_in[2];
    const float* Wq      = (const float*)d_in[3];
    const float* Wk      = (const float*)d_in[4];
    const float* wv      = (const float*)d_in[5];
    float* out  = (float*)d_out;
    float* qpc  = (float*)d_ws;                    // (B*TQ, H)        2 MB
    float* kpc4 = qpc + B * TQ * H;                // (B, H/4, TK, 4)  2 MB

    dim3 gproj(B * TQ / 64, H / 64, 2);
    proj_kernel<<<gproj, 256, 0, stream>>>(queries, keys, Wq, Wk, qpc, kpc4);
    attn_kernel<<<B * (TQ / QB), 512, 0, stream>>>(qpc, kpc4, wv, values, out);
}

// Round 9
// 58.824 us; speedup vs baseline: 1.2486x; 1.1382x over previous
//
#include <hip/hip_runtime.h>

typedef float v2f __attribute__((ext_vector_type(2)));

namespace {
constexpr int B   = 8;
constexpr int TQ  = 256;
constexpr int TK  = 256;
constexpr int DQK = 512;
constexpr int DV  = 512;
constexpr int H   = 256;
constexpr int QB  = 4;           // q rows per attn block
constexpr float C2LOG2E   = 2.8853900817779268f;   // 2*log2(e)
constexpr float NEG2LOG2E = -2.8853900817779268f;
} // namespace

// Fused projections -> EXPONENTIATED outputs (exp2 of scaled projection):
//  z==0: qpc[b*TQ+q][h]       = exp2( (queries @ Wq)[row][h] * 2log2e )
//  z==1: kpc4[b][h/4][k][h&3] = exp2( (keys    @ Wk)[row][h] * 2log2e )
// Then exp2(qp+kp) == qpc * kpc4 elementwise — removes exp2 from the
// O(B*TQ*TK*H) attn inner loop entirely (only rcp remains).
// BM=32 so grid = 512 blocks = 2 blocks/CU (was 1 at BM=64).
__global__ __launch_bounds__(256)
void proj_kernel(const float* __restrict__ Q, const float* __restrict__ Kin,
                 const float* __restrict__ Wq, const float* __restrict__ Wk,
                 float* __restrict__ qpc, float* __restrict__ kpc4)
{
    constexpr int BM = 32, BN = 64, BK = 16;
    __shared__ float As[BK][BM];   // A tile stored transposed (k-major)
    __shared__ float Bs[BK][BN];

    const bool kside = (blockIdx.z == 1);
    const float* A = kside ? Kin : Q;
    const float* W = kside ? Wk  : Wq;
    const int m0 = blockIdx.x * BM;
    const int n0 = blockIdx.y * BN;
    const int tid = threadIdx.x;
    const int tx = tid & 15;        // col group (4 cols)
    const int ty = tid >> 4;        // row group (2 rows)
    const int ar = tid >> 3, ac2 = (tid & 7) * 2;   // A load: row ar, k ac2..+1
    const int br = tid >> 4, bc4 = (tid & 15) * 4;  // B load: k br, col bc4..+3

    // prefetch first tiles into registers
    float2 av = *(const float2*)(A + (m0 + ar) * DQK + ac2);
    float4 bv = *(const float4*)(W + br * H + n0 + bc4);

    v2f acc[2][2] = {};
    for (int k0 = 0; k0 < DQK; k0 += BK) {
        __syncthreads();   // previous iteration's LDS reads complete
        As[ac2 + 0][ar] = av.x;
        As[ac2 + 1][ar] = av.y;
        *(float4*)&Bs[br][bc4] = bv;
        __syncthreads();
        if (k0 + BK < DQK) {   // prefetch next tiles (hidden under fma chain)
            av = *(const float2*)(A + (m0 + ar) * DQK + k0 + BK + ac2);
            bv = *(const float4*)(W + (k0 + BK + br) * H + n0 + bc4);
        }
        #pragma unroll
        for (int kk = 0; kk < BK; ++kk) {
            float2 a2 = *(const float2*)&As[kk][ty * 2];
            float4 b4 = *(const float4*)&Bs[kk][tx * 4];
            v2f blo = {b4.x, b4.y}, bhi = {b4.z, b4.w};
            v2f ax = {a2.x, a2.x}, ay = {a2.y, a2.y};
            acc[0][0] = __builtin_elementwise_fma(ax, blo, acc[0][0]);
            acc[0][1] = __builtin_elementwise_fma(ax, bhi, acc[0][1]);
            acc[1][0] = __builtin_elementwise_fma(ay, blo, acc[1][0]);
            acc[1][1] = __builtin_elementwise_fma(ay, bhi, acc[1][1]);
        }
    }

    if (!kside) {
        #pragma unroll
        for (int i = 0; i < 2; ++i) {
            float4 r;
            r.x = __builtin_amdgcn_exp2f(acc[i][0].x * C2LOG2E);
            r.y = __builtin_amdgcn_exp2f(acc[i][0].y * C2LOG2E);
            r.z = __builtin_amdgcn_exp2f(acc[i][1].x * C2LOG2E);
            r.w = __builtin_amdgcn_exp2f(acc[i][1].y * C2LOG2E);
            *(float4*)(qpc + (m0 + ty * 2 + i) * H + n0 + tx * 4) = r;
        }
    } else {
        const int h = n0 + tx * 4;     // multiple of 4
        #pragma unroll
        for (int i = 0; i < 2; ++i) {
            const int row = m0 + ty * 2 + i;   // = b*256 + k
            const int bb = row >> 8, kk = row & 255;
            float4 r;
            r.x = __builtin_amdgcn_exp2f(acc[i][0].x * C2LOG2E);
            r.y = __builtin_amdgcn_exp2f(acc[i][0].y * C2LOG2E);
            r.z = __builtin_amdgcn_exp2f(acc[i][1].x * C2LOG2E);
            r.w = __builtin_amdgcn_exp2f(acc[i][1].y * C2LOG2E);
            *(float4*)(kpc4 + ((bb * (H / 4) + (h >> 2)) * TK + kk) * 4) = r;
        }
    }
}

// Fused scores + softmax + PV. Block = (b, qgroup of 4), 512 threads, grid 512.
// Score: thread = (kpair = tid&127 -> k=2kp,2kp+1; hg = tid>>7 owns 64 h).
//   Inner: r = rcp(eq*ek + 1)  — ONE trans op per element (exp2 precomputed),
//   one eq broadcast ds_read serves 2k x 4q = 8 elements.
// Softmax without max-subtraction (logits bounded; overflow limit is exact).
// PV: thread (c = tid&255 owns cols c,c+256; kh = tid>>8 owns 128 k).
__global__ __launch_bounds__(512)
void attn_kernel(const float* __restrict__ qpc, const float* __restrict__ kpc4,
                 const float* __restrict__ wv, const float* __restrict__ values,
                 float* __restrict__ out)
{
    __shared__ float qlds[H][QB];        // 4 KB [h][q] (eq, q-major)
    __shared__ float wlds[H];            // 1 KB
    __shared__ float elds[QB][TK];       // 4 KB
    __shared__ float rowsum[QB];
    __shared__ float accbuf[4][QB][TK];  // 16 KB score partials; pv reuses as [2][QB][DV]

    const int b   = blockIdx.x >> 6;     // 64 q-groups per batch
    const int q0  = (blockIdx.x & 63) * QB;
    const int tid = threadIdx.x;

    for (int i = tid; i < QB * H; i += 512) {
        const int h = i >> 2, q = i & 3;
        qlds[h][q] = qpc[(b * TQ + q0 + q) * H + h];
    }
    if (tid < H) wlds[tid] = wv[tid];
    __syncthreads();

    // ---- score: 2 k-columns, 64 h per thread ----
    {
        const int kp = tid & 127;            // k pair: 2kp, 2kp+1
        const int hg = tid >> 7;             // 0..3
        const int h0 = hg * 64;
        const float4* kc = (const float4*)kpc4 + (b * (H / 4) + (h0 >> 2)) * TK + 2 * kp;
        v2f a01a = {0.f, 0.f}, a23a = {0.f, 0.f};   // k even: q01, q23
        v2f a01b = {0.f, 0.f}, a23b = {0.f, 0.f};   // k odd
        #pragma unroll 4
        for (int h4 = 0; h4 < 16; ++h4) {
            float4 kva4 = kc[h4 * TK];       // ek for k=2kp, 4 h
            float4 kvb4 = kc[h4 * TK + 1];   // ek for k=2kp+1
            float4 w4 = *(const float4*)&wlds[h0 + h4 * 4];
            #pragma unroll
            for (int j = 0; j < 4; ++j) {
                const int h = h0 + h4 * 4 + j;
                const float ea = (j == 0) ? kva4.x : (j == 1) ? kva4.y : (j == 2) ? kva4.z : kva4.w;
                const float eb = (j == 0) ? kvb4.x : (j == 1) ? kvb4.y : (j == 2) ? kvb4.z : kvb4.w;
                const float wj = (j == 0) ? w4.x  : (j == 1) ? w4.y  : (j == 2) ? w4.z  : w4.w;
                float4 qa = *(const float4*)&qlds[h][0];   // broadcast eq (4 q)
                v2f q01 = {qa.x, qa.y}, q23 = {qa.z, qa.w};
                v2f ea2 = {ea, ea}, eb2 = {eb, eb}, w2 = {wj, wj};
                v2f one = {1.0f, 1.0f};
                v2f d0a = __builtin_elementwise_fma(q01, ea2, one);  // eq*ek + 1
                v2f d1a = __builtin_elementwise_fma(q23, ea2, one);
                v2f d0b = __builtin_elementwise_fma(q01, eb2, one);
                v2f d1b = __builtin_elementwise_fma(q23, eb2, one);
                v2f r0a, r1a, r0b, r1b;
                r0a.x = __builtin_amdgcn_rcpf(d0a.x);
                r0a.y = __builtin_amdgcn_rcpf(d0a.y);
                r1a.x = __builtin_amdgcn_rcpf(d1a.x);
                r1a.y = __builtin_amdgcn_rcpf(d1a.y);
                r0b.x = __builtin_amdgcn_rcpf(d0b.x);
                r0b.y = __builtin_amdgcn_rcpf(d0b.y);
                r1b.x = __builtin_amdgcn_rcpf(d1b.x);
                r1b.y = __builtin_amdgcn_rcpf(d1b.y);
                a01a = __builtin_elementwise_fma(w2, r0a, a01a);
                a23a = __builtin_elementwise_fma(w2, r1a, a23a);
                a01b = __builtin_elementwise_fma(w2, r0b, a01b);
                a23b = __builtin_elementwise_fma(w2, r1b, a23b);
            }
        }
        accbuf[hg][0][2 * kp]     = a01a.x;
        accbuf[hg][1][2 * kp]     = a01a.y;
        accbuf[hg][2][2 * kp]     = a23a.x;
        accbuf[hg][3][2 * kp]     = a23a.y;
        accbuf[hg][0][2 * kp + 1] = a01b.x;
        accbuf[hg][1][2 * kp + 1] = a01b.y;
        accbuf[hg][2][2 * kp + 1] = a23b.x;
        accbuf[hg][3][2 * kp + 1] = a23b.y;
    }
    __syncthreads();

    // ---- combine h-groups -> e = exp2(-2log2e * acc)  (no max needed) ----
    for (int i = tid; i < QB * TK; i += 512) {
        const int q = i >> 8, kk = i & 255;
        float s = (accbuf[0][q][kk] + accbuf[1][q][kk]) +
                  (accbuf[2][q][kk] + accbuf[3][q][kk]);
        elds[q][kk] = __builtin_amdgcn_exp2f(s * NEG2LOG2E);
    }
    __syncthreads();

    // ---- rowsum: wave w reduces row (w&3); waves 4-7 duplicate harmlessly --
    {
        const int q = (tid >> 6) & 3, lane = tid & 63;
        float4 v = *(const float4*)&elds[q][lane * 4];
        float s = (v.x + v.y) + (v.z + v.w);
        #pragma unroll
        for (int off = 1; off < 64; off <<= 1)
            s += __shfl_xor(s, off);
        if (tid < 256 && lane == 0) rowsum[q] = s;
    }
    __syncthreads();

    // ---- PV: kh owns 128 k; thread owns cols c, c+256 (packed pair) ----
    {
        const int c = tid & 255, kh = tid >> 8;
        const float* vb = values + (b * TK + kh * 128) * DV;
        float* pvout = &accbuf[0][0][0];   // reuse as [2][QB][DV]
        v2f o[QB] = {};
        for (int kk = 0; kk < 128; ++kk) {
            v2f vv = {vb[kk * DV + c], vb[kk * DV + c + 256]};
            const int kc = kh * 128 + kk;
            #pragma unroll
            for (int q = 0; q < QB; ++q) {
                float e = elds[q][kc];                 // broadcast
                v2f e2 = {e, e};
                o[q] = __builtin_elementwise_fma(e2, vv, o[q]);   // v_pk_fma_f32
            }
        }
        #pragma unroll
        for (int q = 0; q < QB; ++q) {
            pvout[(kh * QB + q) * DV + c]       = o[q].x;
            pvout[(kh * QB + q) * DV + c + 256] = o[q].y;
        }
    }
    __syncthreads();

    {
        const float* pvout = &accbuf[0][0][0];
        for (int i = tid; i < QB * DV; i += 512) {
            const int q = i >> 9, c = i & 511;
            float val = (pvout[q * DV + c] + pvout[(QB + q) * DV + c]) *
                        __builtin_amdgcn_rcpf(rowsum[q]);
            out[(b * TQ + q0 + q) * DV + c] = val;
        }
    }
}

extern "C" void kernel_launch(void* const* d_in, const int* in_sizes, int n_in,
                              void* d_out, int out_size, void* d_ws, size_t ws_size,
                              hipStream_t stream)
{
    const float* queries = (const float*)d_in[0];
    const float* keys    = (const float*)d_in[1];
    const float* values  = (const float*)d_in[2];
    const float* Wq      = (const float*)d_in[3];
    const float* Wk      = (const float*)d_in[4];
    const float* wv      = (const float*)d_in[5];
    float* out  = (float*)d_out;
    float* qpc  = (float*)d_ws;                    // (B*TQ, H)        2 MB  (exp'd)
    float* kpc4 = qpc + B * TQ * H;                // (B, H/4, TK, 4)  2 MB  (exp'd)

    dim3 gproj(B * TQ / 32, H / 64, 2);
    proj_kernel<<<gproj, 256, 0, stream>>>(queries, keys, Wq, Wk, qpc, kpc4);
    attn_kernel<<<B * (TQ / QB), 512, 0, stream>>>(qpc, kpc4, wv, values, out);
}

// Round 10
// 46.673 us; speedup vs baseline: 1.5736x; 1.2603x over previous
//
#include <hip/hip_runtime.h>

typedef float v2f __attribute__((ext_vector_type(2)));
typedef short bf16x8 __attribute__((ext_vector_type(8)));
typedef float f32x4 __attribute__((ext_vector_type(4)));

namespace {
constexpr int B   = 8;
constexpr int TQ  = 256;
constexpr int TK  = 256;
constexpr int DQK = 512;
constexpr int DV  = 512;
constexpr int H   = 256;
constexpr int QB  = 4;           // q rows per attn block
constexpr float C2LOG2E   = 2.8853900817779268f;   // 2*log2(e)
constexpr float NEG2LOG2E = -2.8853900817779268f;
} // namespace

__device__ __forceinline__ uint32_t f2u(float x) { return __builtin_bit_cast(uint32_t, x); }
__device__ __forceinline__ float u2f(uint32_t x) { return __builtin_bit_cast(float, x); }
// pack bf16(x) into low16, bf16(y) into high16 (truncation; lo-term absorbs error)
__device__ __forceinline__ uint32_t pack_hi(float x, float y) {
    return (f2u(y) & 0xFFFF0000u) | (f2u(x) >> 16);
}

// MFMA projections (bf16 hi/lo split: a*b ~ ah*bh + ah*bl + al*bh), fp32 acc.
//  z==0: qpc[b*TQ+q][h]       = exp2( (queries @ Wq)[row][h] * 2log2e )
//  z==1: kpc4[b][h/4][k][h&3] = exp2( (keys    @ Wk)[row][h] * 2log2e )
// BM=64, BN=32, BK=32; 4 waves in 2x2, wave tile 32m x 16n; grid 512 = 2/CU.
__global__ __launch_bounds__(256)
void proj_kernel(const float* __restrict__ Q, const float* __restrict__ Kin,
                 const float* __restrict__ Wq, const float* __restrict__ Wk,
                 float* __restrict__ qpc, float* __restrict__ kpc4)
{
    __shared__ short Ahi[4][64][8];   // [kgroup][m][8 bf16] = 4 KB
    __shared__ short Alo[4][64][8];
    __shared__ short Bhi[4][32][8];   // [kgroup][n][8 bf16] = 2 KB
    __shared__ short Blo[4][32][8];

    const bool kside = (blockIdx.z == 1);
    const float* A = kside ? Kin : Q;
    const float* W = kside ? Wk  : Wq;
    const int m0 = blockIdx.x * 64;
    const int n0 = blockIdx.y * 32;
    const int tid = threadIdx.x;

    // staging assignments
    const int am = tid >> 2, ag = tid & 3;          // A: row am, k = ag*8..+7
    const int bk = tid >> 3, bn4 = (tid & 7) * 4;   // B: k row bk, cols bn4..+3
    const float4* aptr = (const float4*)(A + (m0 + am) * DQK) + ag * 2;
    const float*  wptr = W + bk * H + n0 + bn4;

    // wave/frag assignments
    const int w = tid >> 6, l = tid & 63;
    const int wm = (w >> 1) * 32, wn = (w & 1) * 16;
    const int fg = l >> 4;                // k-group
    const int fr = l & 15;                // frag row/col

    // prefetch step 0
    float4 a0 = aptr[0], a1 = aptr[1];
    float4 bv = *(const float4*)wptr;

    f32x4 acc0 = {0.f, 0.f, 0.f, 0.f};
    f32x4 acc1 = {0.f, 0.f, 0.f, 0.f};

    for (int s = 0; s < 16; ++s) {
        __syncthreads();   // previous iteration's frag reads complete
        {
            // A tile: hi/lo packs, one 16B write each
            float ah0 = u2f(f2u(a0.x) & 0xFFFF0000u), ah1 = u2f(f2u(a0.y) & 0xFFFF0000u);
            float ah2 = u2f(f2u(a0.z) & 0xFFFF0000u), ah3 = u2f(f2u(a0.w) & 0xFFFF0000u);
            float ah4 = u2f(f2u(a1.x) & 0xFFFF0000u), ah5 = u2f(f2u(a1.y) & 0xFFFF0000u);
            float ah6 = u2f(f2u(a1.z) & 0xFFFF0000u), ah7 = u2f(f2u(a1.w) & 0xFFFF0000u);
            int4 hw, lw;
            hw.x = (int)pack_hi(a0.x, a0.y); hw.y = (int)pack_hi(a0.z, a0.w);
            hw.z = (int)pack_hi(a1.x, a1.y); hw.w = (int)pack_hi(a1.z, a1.w);
            lw.x = (int)pack_hi(a0.x - ah0, a0.y - ah1);
            lw.y = (int)pack_hi(a0.z - ah2, a0.w - ah3);
            lw.z = (int)pack_hi(a1.x - ah4, a1.y - ah5);
            lw.w = (int)pack_hi(a1.z - ah6, a1.w - ah7);
            *(int4*)&Ahi[ag][am][0] = hw;
            *(int4*)&Alo[ag][am][0] = lw;
            // B tile: transpose to [kgroup][n][slot], scalar b16 writes
            const int g = bk >> 3, slot = bk & 7;
            float bb[4] = {bv.x, bv.y, bv.z, bv.w};
            #pragma unroll
            for (int i = 0; i < 4; ++i) {
                uint32_t u = f2u(bb[i]);
                float hf = u2f(u & 0xFFFF0000u);
                Bhi[g][bn4 + i][slot] = (short)(u >> 16);
                Blo[g][bn4 + i][slot] = (short)(f2u(bb[i] - hf) >> 16);
            }
        }
        __syncthreads();
        if (s < 15) {   // prefetch next K-tile (hides under MFMA chain)
            a0 = aptr[s * 8 + 8];
            a1 = aptr[s * 8 + 9];
            bv = *(const float4*)(wptr + (s + 1) * 32 * H);
        }
        bf16x8 ah_0 = *(const bf16x8*)&Ahi[fg][wm + fr][0];
        bf16x8 ah_1 = *(const bf16x8*)&Ahi[fg][wm + 16 + fr][0];
        bf16x8 al_0 = *(const bf16x8*)&Alo[fg][wm + fr][0];
        bf16x8 al_1 = *(const bf16x8*)&Alo[fg][wm + 16 + fr][0];
        bf16x8 bh   = *(const bf16x8*)&Bhi[fg][wn + fr][0];
        bf16x8 bl   = *(const bf16x8*)&Blo[fg][wn + fr][0];
        acc0 = __builtin_amdgcn_mfma_f32_16x16x32_bf16(ah_0, bh, acc0, 0, 0, 0);
        acc1 = __builtin_amdgcn_mfma_f32_16x16x32_bf16(ah_1, bh, acc1, 0, 0, 0);
        acc0 = __builtin_amdgcn_mfma_f32_16x16x32_bf16(ah_0, bl, acc0, 0, 0, 0);
        acc1 = __builtin_amdgcn_mfma_f32_16x16x32_bf16(ah_1, bl, acc1, 0, 0, 0);
        acc0 = __builtin_amdgcn_mfma_f32_16x16x32_bf16(al_0, bh, acc0, 0, 0, 0);
        acc1 = __builtin_amdgcn_mfma_f32_16x16x32_bf16(al_1, bh, acc1, 0, 0, 0);
    }

    // epilogue: C row = (l>>4)*4 + r (+ mi*16 + wm), col = (l&15) + wn
    const int col = n0 + wn + fr;
    #pragma unroll
    for (int mi = 0; mi < 2; ++mi) {
        f32x4 acc = mi ? acc1 : acc0;
        #pragma unroll
        for (int r = 0; r < 4; ++r) {
            const int row = m0 + wm + mi * 16 + fg * 4 + r;
            float val = __builtin_amdgcn_exp2f(acc[r] * C2LOG2E);
            if (!kside) {
                qpc[row * H + col] = val;
            } else {
                const int bb2 = row >> 8, kk = row & 255;
                kpc4[((bb2 * (H / 4) + (col >> 2)) * TK + kk) * 4 + (col & 3)] = val;
            }
        }
    }
}

// Fused scores + softmax + PV. Block = (b, qgroup of 4), 512 threads, grid 512.
// Score: thread = (kpair = tid&127 -> k=2kp,2kp+1; hg = tid>>7 owns 64 h).
//   Inner: r = rcp(eq*ek + 1)  — ONE trans op per element (exp2 precomputed),
//   one eq broadcast ds_read serves 2k x 4q = 8 elements.
// Softmax without max-subtraction (logits bounded; overflow limit is exact).
// PV: thread (c = tid&255 owns cols c,c+256; kh = tid>>8 owns 128 k).
__global__ __launch_bounds__(512)
void attn_kernel(const float* __restrict__ qpc, const float* __restrict__ kpc4,
                 const float* __restrict__ wv, const float* __restrict__ values,
                 float* __restrict__ out)
{
    __shared__ float qlds[H][QB];        // 4 KB [h][q] (eq, q-major)
    __shared__ float wlds[H];            // 1 KB
    __shared__ float elds[QB][TK];       // 4 KB
    __shared__ float rowsum[QB];
    __shared__ float accbuf[4][QB][TK];  // 16 KB score partials; pv reuses as [2][QB][DV]

    const int b   = blockIdx.x >> 6;     // 64 q-groups per batch
    const int q0  = (blockIdx.x & 63) * QB;
    const int tid = threadIdx.x;

    for (int i = tid; i < QB * H; i += 512) {
        const int h = i >> 2, q = i & 3;
        qlds[h][q] = qpc[(b * TQ + q0 + q) * H + h];
    }
    if (tid < H) wlds[tid] = wv[tid];
    __syncthreads();

    // ---- score: 2 k-columns, 64 h per thread ----
    {
        const int kp = tid & 127;            // k pair: 2kp, 2kp+1
        const int hg = tid >> 7;             // 0..3
        const int h0 = hg * 64;
        const float4* kc = (const float4*)kpc4 + (b * (H / 4) + (h0 >> 2)) * TK + 2 * kp;
        v2f a01a = {0.f, 0.f}, a23a = {0.f, 0.f};   // k even: q01, q23
        v2f a01b = {0.f, 0.f}, a23b = {0.f, 0.f};   // k odd
        #pragma unroll 4
        for (int h4 = 0; h4 < 16; ++h4) {
            float4 kva4 = kc[h4 * TK];       // ek for k=2kp, 4 h
            float4 kvb4 = kc[h4 * TK + 1];   // ek for k=2kp+1
            float4 w4 = *(const float4*)&wlds[h0 + h4 * 4];
            #pragma unroll
            for (int j = 0; j < 4; ++j) {
                const int h = h0 + h4 * 4 + j;
                const float ea = (j == 0) ? kva4.x : (j == 1) ? kva4.y : (j == 2) ? kva4.z : kva4.w;
                const float eb = (j == 0) ? kvb4.x : (j == 1) ? kvb4.y : (j == 2) ? kvb4.z : kvb4.w;
                const float wj = (j == 0) ? w4.x  : (j == 1) ? w4.y  : (j == 2) ? w4.z  : w4.w;
                float4 qa = *(const float4*)&qlds[h][0];   // broadcast eq (4 q)
                v2f q01 = {qa.x, qa.y}, q23 = {qa.z, qa.w};
                v2f ea2 = {ea, ea}, eb2 = {eb, eb}, w2 = {wj, wj};
                v2f one = {1.0f, 1.0f};
                v2f d0a = __builtin_elementwise_fma(q01, ea2, one);  // eq*ek + 1
                v2f d1a = __builtin_elementwise_fma(q23, ea2, one);
                v2f d0b = __builtin_elementwise_fma(q01, eb2, one);
                v2f d1b = __builtin_elementwise_fma(q23, eb2, one);
                v2f r0a, r1a, r0b, r1b;
                r0a.x = __builtin_amdgcn_rcpf(d0a.x);
                r0a.y = __builtin_amdgcn_rcpf(d0a.y);
                r1a.x = __builtin_amdgcn_rcpf(d1a.x);
                r1a.y = __builtin_amdgcn_rcpf(d1a.y);
                r0b.x = __builtin_amdgcn_rcpf(d0b.x);
                r0b.y = __builtin_amdgcn_rcpf(d0b.y);
                r1b.x = __builtin_amdgcn_rcpf(d1b.x);
                r1b.y = __builtin_amdgcn_rcpf(d1b.y);
                a01a = __builtin_elementwise_fma(w2, r0a, a01a);
                a23a = __builtin_elementwise_fma(w2, r1a, a23a);
                a01b = __builtin_elementwise_fma(w2, r0b, a01b);
                a23b = __builtin_elementwise_fma(w2, r1b, a23b);
            }
        }
        accbuf[hg][0][2 * kp]     = a01a.x;
        accbuf[hg][1][2 * kp]     = a01a.y;
        accbuf[hg][2][2 * kp]     = a23a.x;
        accbuf[hg][3][2 * kp]     = a23a.y;
        accbuf[hg][0][2 * kp + 1] = a01b.x;
        accbuf[hg][1][2 * kp + 1] = a01b.y;
        accbuf[hg][2][2 * kp + 1] = a23b.x;
        accbuf[hg][3][2 * kp + 1] = a23b.y;
    }
    __syncthreads();

    // ---- combine h-groups -> e = exp2(-2log2e * acc)  (no max needed) ----
    for (int i = tid; i < QB * TK; i += 512) {
        const int q = i >> 8, kk = i & 255;
        float s = (accbuf[0][q][kk] + accbuf[1][q][kk]) +
                  (accbuf[2][q][kk] + accbuf[3][q][kk]);
        elds[q][kk] = __builtin_amdgcn_exp2f(s * NEG2LOG2E);
    }
    __syncthreads();

    // ---- rowsum: wave w reduces row (w&3); waves 4-7 duplicate harmlessly --
    {
        const int q = (tid >> 6) & 3, lane = tid & 63;
        float4 v = *(const float4*)&elds[q][lane * 4];
        float s = (v.x + v.y) + (v.z + v.w);
        #pragma unroll
        for (int off = 1; off < 64; off <<= 1)
            s += __shfl_xor(s, off);
        if (tid < 256 && lane == 0) rowsum[q] = s;
    }
    __syncthreads();

    // ---- PV: kh owns 128 k; thread owns cols c, c+256 (packed pair) ----
    {
        const int c = tid & 255, kh = tid >> 8;
        const float* vb = values + (b * TK + kh * 128) * DV;
        float* pvout = &accbuf[0][0][0];   // reuse as [2][QB][DV]
        v2f o[QB] = {};
        for (int kk = 0; kk < 128; ++kk) {
            v2f vv = {vb[kk * DV + c], vb[kk * DV + c + 256]};
            const int kc = kh * 128 + kk;
            #pragma unroll
            for (int q = 0; q < QB; ++q) {
                float e = elds[q][kc];                 // broadcast
                v2f e2 = {e, e};
                o[q] = __builtin_elementwise_fma(e2, vv, o[q]);   // v_pk_fma_f32
            }
        }
        #pragma unroll
        for (int q = 0; q < QB; ++q) {
            pvout[(kh * QB + q) * DV + c]       = o[q].x;
            pvout[(kh * QB + q) * DV + c + 256] = o[q].y;
        }
    }
    __syncthreads();

    {
        const float* pvout = &accbuf[0][0][0];
        for (int i = tid; i < QB * DV; i += 512) {
            const int q = i >> 9, c = i & 511;
            float val = (pvout[q * DV + c] + pvout[(QB + q) * DV + c]) *
                        __builtin_amdgcn_rcpf(rowsum[q]);
            out[(b * TQ + q0 + q) * DV + c] = val;
        }
    }
}

extern "C" void kernel_launch(void* const* d_in, const int* in_sizes, int n_in,
                              void* d_out, int out_size, void* d_ws, size_t ws_size,
                              hipStream_t stream)
{
    const float* queries = (const float*)d_in[0];
    const float* keys    = (const float*)d_in[1];
    const float* values  = (const float*)d_in[2];
    const float* Wq      = (const float*)d_in[3];
    const float* Wk      = (const float*)d_in[4];
    const float* wv      = (const float*)d_in[5];
    float* out  = (float*)d_out;
    float* qpc  = (float*)d_ws;                    // (B*TQ, H)        2 MB  (exp'd)
    float* kpc4 = qpc + B * TQ * H;                // (B, H/4, TK, 4)  2 MB  (exp'd)

    dim3 gproj(B * TQ / 64, H / 32, 2);
    proj_kernel<<<gproj, 256, 0, stream>>>(queries, keys, Wq, Wk, qpc, kpc4);
    attn_kernel<<<B * (TQ / QB), 512, 0, stream>>>(qpc, kpc4, wv, values, out);
}